// Round 14
// baseline (291.660 us; speedup 1.0000x reference)
//
#include <hip/hip_runtime.h>
#include <hip/hip_bf16.h>

typedef __bf16 bf16x8 __attribute__((ext_vector_type(8)));
typedef float f32x4 __attribute__((ext_vector_type(4)));

#define B_ 16
#define N_ 2048
#define C_ 512
#define D_ 64

__device__ __forceinline__ float bf2f(ushort u) {
    union { uint i; float f; } w; w.i = ((uint)u) << 16; return w.f;
}
__device__ __forceinline__ ushort f2bf(float f) {
    union { float f; uint i; } w; w.f = f;
    uint u = w.i;
    u = (u + 0x7fffu + ((u >> 16) & 1u)) >> 16;
    return (ushort)u;
}
__device__ __forceinline__ __bf16 u2b(ushort u) {
    union { ushort s; __bf16 b; } w; w.s = u; return w.b;
}
__device__ __forceinline__ bf16x8 ld8u(const ushort* p) { return *(const bf16x8*)p; }
__device__ __forceinline__ bf16x8 ld8f(const float* p) {
    f32x4 a = *(const f32x4*)p;
    f32x4 b = *(const f32x4*)(p + 4);
    bf16x8 r;
    r[0] = u2b(f2bf(a[0])); r[1] = u2b(f2bf(a[1]));
    r[2] = u2b(f2bf(a[2])); r[3] = u2b(f2bf(a[3]));
    r[4] = u2b(f2bf(b[0])); r[5] = u2b(f2bf(b[1]));
    r[6] = u2b(f2bf(b[2])); r[7] = u2b(f2bf(b[3]));
    return r;
}

// async global->LDS, 16 B per lane; LDS dest = wave-uniform base + lane*16
__device__ __forceinline__ void gload16(const ushort* g, ushort* l) {
    __builtin_amdgcn_global_load_lds(
        (const __attribute__((address_space(1))) void*)g,
        (__attribute__((address_space(3))) void*)l, 16, 0, 0);
}

// Decide whether float tensors are stored as f32 or bf16 (bench: f32).
__global__ void probe_kernel(const void* x, int* flag) {
    int lane = threadIdx.x & 63;
    ushort u = ((const ushort*)x)[lane * 2];
    float v = fabsf(bf2f(u));
    bool sane = (v > 9.3e-10f) && (v < 1.1e9f) && (v == v);
    unsigned long long m = __ballot(sane);
    if (threadIdx.x == 0) *flag = (__popcll(m) >= 48) ? 0 : 1;  // 0=bf16, 1=f32
}

// One memory-bound pass: X -> xbf (bf16), pack [Wq|Wk|Wv] -> wall (bf16).
__global__ void convert_kernel(const void* __restrict__ X,
                               const void* __restrict__ Wq_,
                               const void* __restrict__ Wk_,
                               const void* __restrict__ Wv_,
                               ushort* __restrict__ xbf,
                               ushort* __restrict__ wall,
                               const int* __restrict__ flag) {
    const int isf32 = *flag;
    const size_t NX  = (size_t)B_ * N_ * C_;   // 16,777,216
    const size_t NWQ = (size_t)D_ * C_;        // 32,768
    const size_t NWV = (size_t)C_ * C_;        // 262,144
    const size_t total8 = (NX + 2 * NWQ + NWV) / 8;
    const size_t stride = (size_t)gridDim.x * blockDim.x;
    for (size_t v = (size_t)blockIdx.x * blockDim.x + threadIdx.x; v < total8; v += stride) {
        size_t e = v * 8;
        const void* src;
        size_t off;
        ushort* dst;
        if (e < NX)                { src = X;   off = e;                dst = xbf + e; }
        else if (e < NX + NWQ)     { src = Wq_; off = e - NX;           dst = wall + (e - NX); }
        else if (e < NX + 2 * NWQ) { src = Wk_; off = e - NX - NWQ;     dst = wall + (e - NX); }
        else                       { src = Wv_; off = e - NX - 2 * NWQ; dst = wall + (e - NX); }
        bf16x8 r = isf32 ? ld8f((const float*)src + off) : ld8u((const ushort*)src + off);
        *(bf16x8*)dst = r;
    }
}

// Merged Q+K+V projection, bf16-in, m97 structure (global_load_lds + XOR
// swizzle). v-blocks (n0>=128) use a transpose-in-LDS epilogue (coalesced
// vt store). XCD-aware block swizzle: 1280 blocks = 8 XCD x 160; the 5
// n-tiles sharing one A(m)-panel run consecutively on the SAME XCD so the
// panel is fetched once per XCD L2 instead of 5x.
#define TP_ 136   // transpose LDS pitch (ushorts): 16B-aligned rows, ~2-way banks
__launch_bounds__(256, 2)
__global__ void proj_all(const ushort* __restrict__ xbf,
                         const ushort* __restrict__ wall,
                         const void* __restrict__ bq_,
                         const void* __restrict__ bk_,
                         const void* __restrict__ bv_,
                         ushort* __restrict__ outq,
                         ushort* __restrict__ outk,
                         ushort* __restrict__ outv,
                         const int* __restrict__ flag) {
    // union: staging lA|lB (32 KB) vs transpose buffer T (34 KB)
    __shared__ __align__(16) char smem[128 * TP_ * 2];
    ushort* lA = (ushort*)smem;                 // [128*64]
    ushort* lB = lA + 128 * 64;                 // [128*64]
    ushort* T  = (ushort*)smem;                 // [128][TP_]

    const int tid  = threadIdx.x;
    const int wave = tid >> 6, lane = tid & 63;
    const int quad = lane >> 4, li = lane & 15;
    const int wr = (wave & 1) * 64;
    const int wc = (wave >> 1) * 64;
    // XCD swizzle: lin -> (xcd = lin&7, idx = lin>>3), virt = xcd*160+idx;
    // n fastest within virt so same-m panels stay on one XCD.
    const int lin  = blockIdx.x;
    const int virt = (lin & 7) * 160 + (lin >> 3);
    const int n0 = (virt % 5) * 128;
    const int m0 = (virt / 5) * 128;

    const int lrow8 = lane >> 3;
    const int lseg  = (lane & 7) ^ (lrow8 & 7);

    f32x4 acc[4][4];
    #pragma unroll
    for (int i = 0; i < 4; ++i)
        #pragma unroll
        for (int j = 0; j < 4; ++j) acc[i][j] = (f32x4){0.f, 0.f, 0.f, 0.f};

    for (int k0 = 0; k0 < C_; k0 += 64) {
        __syncthreads();
        #pragma unroll
        for (int i = 0; i < 4; ++i) {
            int rbase = wave * 32 + i * 8;
            gload16(xbf  + (size_t)(m0 + rbase + lrow8) * C_ + k0 + lseg * 8,
                    &lA[rbase * 64]);
            gload16(wall + (size_t)(n0 + rbase + lrow8) * C_ + k0 + lseg * 8,
                    &lB[rbase * 64]);
        }
        __syncthreads();
        #pragma unroll
        for (int ks = 0; ks < 2; ++ks) {
            bf16x8 af[4], bfr[4];
            #pragma unroll
            for (int i = 0; i < 4; ++i) {
                int row = wr + i * 16 + li;
                af[i] = *(const bf16x8*)&lA[row * 64 + (((ks * 4 + quad) ^ (li & 7)) * 8)];
            }
            #pragma unroll
            for (int j = 0; j < 4; ++j) {
                int row = wc + j * 16 + li;
                bfr[j] = *(const bf16x8*)&lB[row * 64 + (((ks * 4 + quad) ^ (li & 7)) * 8)];
            }
            #pragma unroll
            for (int i = 0; i < 4; ++i)
                #pragma unroll
                for (int j = 0; j < 4; ++j)
                    acc[i][j] = __builtin_amdgcn_mfma_f32_16x16x32_bf16(
                        af[i], bfr[j], acc[i][j], 0, 0, 0);
        }
    }

    const int isf32 = *flag;
    if (n0 == 0) {
        // q | k block: per-element epilogue (8 MB total, ~2x amp — negligible)
        #pragma unroll
        for (int j2 = 0; j2 < 4; ++j2) {
            int c = wc + j2 * 16 + li;
            float bv;
            if (!isf32) {
                bv = (c < 64) ? bf2f(((const ushort*)bq_)[c])
                              : bf2f(((const ushort*)bk_)[c - 64]);
            } else {
                bv = (c < 64) ? ((const float*)bq_)[c]
                              : ((const float*)bk_)[c - 64];
            }
            ushort* dst = (c < 64) ? outq : outk;
            int cl = c & 63;
            #pragma unroll
            for (int i = 0; i < 4; ++i)
                #pragma unroll
                for (int j = 0; j < 4; ++j) {
                    int m = m0 + wr + i * 16 + quad * 4 + j;
                    dst[(size_t)m * D_ + cl] = f2bf(acc[i][j2][j] + bv);
                }
        }
    } else {
        // v block: bias + bf16 into transposed LDS [c][m], then coalesced store
        __syncthreads();   // all waves done reading lA/lB before overwrite
        #pragma unroll
        for (int j2 = 0; j2 < 4; ++j2) {
            int cl = wc + j2 * 16 + li;               // local c 0..127
            int cv = (n0 - 128) + cl;                 // global v channel
            float bv = isf32 ? ((const float*)bv_)[cv]
                             : bf2f(((const ushort*)bv_)[cv]);
            #pragma unroll
            for (int i = 0; i < 4; ++i)
                #pragma unroll
                for (int j = 0; j < 4; ++j) {
                    int ml = wr + i * 16 + quad * 4 + j;   // local m 0..127
                    T[cl * TP_ + ml] = f2bf(acc[i][j2][j] + bv);
                }
        }
        __syncthreads();
        const int b      = m0 >> 11;          // batch (m0 multiple of 128)
        const int mlbase = m0 & (N_ - 1);
        const int cm  = tid & 15;             // 16B chunk within row
        const int cr  = tid >> 4;             // row group 0..15
        #pragma unroll
        for (int s = 0; s < 8; ++s) {
            int cl = s * 16 + cr;             // local c row
            int cv = (n0 - 128) + cl;
            bf16x8 vv = *(const bf16x8*)&T[cl * TP_ + cm * 8];
            *(bf16x8*)(outv + ((size_t)(b * C_ + cv)) * N_ + mlbase + cm * 8) = vv;
        }
    }
}

// Fused attention v3: double-buffered V with counted-vmcnt raw barriers
// (T3/T4-lite) + K register prefetch + setprio around PV (T5).
// Launched as TWO half-batch dispatches (b0 = 0, 8) this round so proj_all
// surfaces in the rocprof top-5 (instrumentation; ~free).
__launch_bounds__(512, 4)
__global__ void attn_fused(const ushort* __restrict__ q,
                           const ushort* __restrict__ kk,
                           const ushort* __restrict__ vt,
                           const void* __restrict__ x,
                           const void* __restrict__ gptr,
                           void* __restrict__ out,
                           const int* __restrict__ flag,
                           int b0) {
    __shared__ ushort Vl[2][256 * 64];   // 2 x 32 KB V tile (swizzled, rows=c)
    __shared__ ushort Pl[64 * 64];       //  8 KB P tile (swizzled)
    __shared__ float  ll[64];            // row sums

    const int tid  = threadIdx.x;
    const int wave = tid >> 6, lane = tid & 63;
    const int quad = lane >> 4, li = lane & 15;
    const int wq = wave & 1;          // q-half (32 rows)
    const int wm = wave >> 1;         // 16-wide m-range (QK) / 64-wide c-range (PV)
    const int b  = blockIdx.z + b0;
    const int q0 = blockIdx.x * 64;
    const int c0 = blockIdx.y * 256;

    const ushort* kb = kk + (size_t)b * N_ * D_;
    const ushort* vb = vt + ((size_t)b * C_ + c0) * N_;

    // staging lane constants (pre-swizzled global source -> linear LDS dest)
    const int lrow8 = lane >> 3;               // 0..7
    const int lseg  = (lane & 7) ^ lrow8;      // XOR'd 16B granule

    // Q fragments: rows q0 + wq*32 + i*16 + li
    bf16x8 qf[2][2];
    #pragma unroll
    for (int i = 0; i < 2; ++i)
        #pragma unroll
        for (int ks = 0; ks < 2; ++ks)
            qf[i][ks] = ld8u(q + ((size_t)(b * N_ + q0 + wq * 32 + i * 16 + li)) * D_
                               + ks * 32 + quad * 8);

    f32x4 acc[2][4];   // O rows wq*32+i*16+quad*4+jj, cols c0+wm*64+j*16+li
    #pragma unroll
    for (int i = 0; i < 2; ++i)
        #pragma unroll
        for (int j = 0; j < 4; ++j) acc[i][j] = (f32x4){0.f, 0.f, 0.f, 0.f};

    f32x4 accp[2];     // P rows wq*32+i*16+quad*4+j, m col wm*16+li
    float s4[2][4];
    #pragma unroll
    for (int i = 0; i < 2; ++i) {
        accp[i] = (f32x4){0.f, 0.f, 0.f, 0.f};
        #pragma unroll
        for (int j = 0; j < 4; ++j) s4[i][j] = 0.f;
    }

    // prologue: stage V(0) -> Vl[0]; QK(0) with direct K loads; kreg = K(1)
    #pragma unroll
    for (int it = 0; it < 4; ++it) {
        int rbase = wave * 32 + it * 8;
        gload16(vb + (size_t)(rbase + lrow8) * N_ + lseg * 8, &Vl[0][rbase * 64]);
    }
    {
        bf16x8 k0 = ld8u(kb + (size_t)(wm * 16 + li) * D_ + quad * 8);
        bf16x8 k1 = ld8u(kb + (size_t)(wm * 16 + li) * D_ + 32 + quad * 8);
        accp[0] = __builtin_amdgcn_mfma_f32_16x16x32_bf16(qf[0][0], k0, accp[0], 0, 0, 0);
        accp[1] = __builtin_amdgcn_mfma_f32_16x16x32_bf16(qf[1][0], k0, accp[1], 0, 0, 0);
        accp[0] = __builtin_amdgcn_mfma_f32_16x16x32_bf16(qf[0][1], k1, accp[0], 0, 0, 0);
        accp[1] = __builtin_amdgcn_mfma_f32_16x16x32_bf16(qf[1][1], k1, accp[1], 0, 0, 0);
    }
    bf16x8 kreg0 = ld8u(kb + (size_t)(64 + wm * 16 + li) * D_ + quad * 8);
    bf16x8 kreg1 = ld8u(kb + (size_t)(64 + wm * 16 + li) * D_ + 32 + quad * 8);

    for (int t = 0; t < 32; ++t) {
        const int cur = t & 1;
        // (a) issue V(t+1) stage into the other buffer (async, not waited here)
        if (t < 31) {
            #pragma unroll
            for (int it = 0; it < 4; ++it) {
                int rbase = wave * 32 + it * 8;
                gload16(vb + (size_t)(rbase + lrow8) * N_ + (t + 1) * 64 + lseg * 8,
                        &Vl[cur ^ 1][rbase * 64]);
            }
        }
        // (b) P-write(t): exp(accp) -> swizzled LDS; accumulate row sums
        #pragma unroll
        for (int i = 0; i < 2; ++i)
            #pragma unroll
            for (int j = 0; j < 4; ++j) {
                int r = wq * 32 + i * 16 + quad * 4 + j;
                int m = wm * 16 + li;
                float e = __expf(fminf(accp[i][j], 60.f));
                s4[i][j] += e;
                *(__bf16*)&Pl[r * 64 + (((m >> 3) ^ (r & 7)) * 8) + (m & 7)] = (__bf16)e;
            }
        // (c) QK(t+1) from kreg; (d) prefetch kreg(t+2)
        if (t < 31) {
            f32x4 np0 = (f32x4){0.f, 0.f, 0.f, 0.f};
            f32x4 np1 = (f32x4){0.f, 0.f, 0.f, 0.f};
            np0 = __builtin_amdgcn_mfma_f32_16x16x32_bf16(qf[0][0], kreg0, np0, 0, 0, 0);
            np1 = __builtin_amdgcn_mfma_f32_16x16x32_bf16(qf[1][0], kreg0, np1, 0, 0, 0);
            np0 = __builtin_amdgcn_mfma_f32_16x16x32_bf16(qf[0][1], kreg1, np0, 0, 0, 0);
            np1 = __builtin_amdgcn_mfma_f32_16x16x32_bf16(qf[1][1], kreg1, np1, 0, 0, 0);
            if (t < 30) {
                kreg0 = ld8u(kb + (size_t)((t + 2) * 64 + wm * 16 + li) * D_ + quad * 8);
                kreg1 = ld8u(kb + (size_t)((t + 2) * 64 + wm * 16 + li) * D_ + 32 + quad * 8);
            }
            accp[0] = np0;
            accp[1] = np1;
        }
        // barrier 1: counted vmcnt leaves next-tile loads in flight
        if (t < 30)       asm volatile("s_waitcnt vmcnt(6) lgkmcnt(0)" ::: "memory");
        else if (t == 30) asm volatile("s_waitcnt vmcnt(4) lgkmcnt(0)" ::: "memory");
        else              asm volatile("s_waitcnt vmcnt(0) lgkmcnt(0)" ::: "memory");
        __builtin_amdgcn_sched_barrier(0);
        __builtin_amdgcn_s_barrier();
        __builtin_amdgcn_sched_barrier(0);

        // PV(t): A = P rows (wq half), B = V rows c (wm range)
        __builtin_amdgcn_s_setprio(1);
        #pragma unroll
        for (int ks = 0; ks < 2; ++ks) {
            bf16x8 af[2];
            #pragma unroll
            for (int i = 0; i < 2; ++i)
                af[i] = *(const bf16x8*)&Pl[(wq * 32 + i * 16 + li) * 64
                                            + (((ks * 4 + quad) ^ (li & 7)) * 8)];
            #pragma unroll
            for (int j = 0; j < 4; ++j) {
                bf16x8 vf = *(const bf16x8*)&Vl[cur][(wm * 64 + j * 16 + li) * 64
                                                    + (((ks * 4 + quad) ^ (li & 7)) * 8)];
                #pragma unroll
                for (int i = 0; i < 2; ++i)
                    acc[i][j] = __builtin_amdgcn_mfma_f32_16x16x32_bf16(
                        af[i], vf, acc[i][j], 0, 0, 0);
            }
        }
        __builtin_amdgcn_s_setprio(0);

        // barrier 2: Pl / Vl[cur] reads done block-wide before next overwrite
        __builtin_amdgcn_sched_barrier(0);
        __builtin_amdgcn_s_barrier();
        __builtin_amdgcn_sched_barrier(0);
    }

    // l reduction: shfl over the 16 li lanes, then add the 4 wm-partner waves
    __syncthreads();
    if (tid < 64) ll[tid] = 0.f;
    __syncthreads();
    #pragma unroll
    for (int i = 0; i < 2; ++i)
        #pragma unroll
        for (int j = 0; j < 4; ++j) {
            float s = s4[i][j];
            s += __shfl_xor(s, 1, 64);
            s += __shfl_xor(s, 2, 64);
            s += __shfl_xor(s, 4, 64);
            s += __shfl_xor(s, 8, 64);
            if (li == 0) atomicAdd(&ll[wq * 32 + i * 16 + quad * 4 + j], s);
        }
    __syncthreads();

    const int isf32 = *flag;
    const float g = isf32 ? ((const float*)gptr)[0] : bf2f(((const ushort*)gptr)[0]);
    const ushort* xu = (const ushort*)x;
    const float*  xf = (const float*)x;
    ushort* ou = (ushort*)out;
    float*  of = (float*)out;
    #pragma unroll
    for (int i = 0; i < 2; ++i)
        #pragma unroll
        for (int jj = 0; jj < 4; ++jj) {
            int nl = wq * 32 + i * 16 + quad * 4 + jj;
            float inv = 1.f / ll[nl];
            size_t rowb = ((size_t)(b * N_ + q0 + nl)) * C_;
            #pragma unroll
            for (int j = 0; j < 4; ++j) {
                int cg = c0 + wm * 64 + j * 16 + li;
                size_t idx = rowb + cg;
                float xv  = isf32 ? xf[idx] : bf2f(xu[idx]);
                float val = g * (acc[i][j][jj] * inv) + xv;
                if (isf32) of[idx] = val; else ou[idx] = f2bf(val);
            }
        }
}

extern "C" void kernel_launch(void* const* d_in, const int* in_sizes, int n_in,
                              void* d_out, int out_size, void* d_ws, size_t ws_size,
                              hipStream_t stream) {
    (void)in_sizes; (void)n_in; (void)out_size; (void)ws_size;
    const void* x     = d_in[0];
    const void* Wq    = d_in[1];
    const void* bq    = d_in[2];
    const void* Wk    = d_in[3];
    const void* bk    = d_in[4];
    const void* Wv    = d_in[5];
    const void* bv    = d_in[6];
    const void* gamma = d_in[7];

    // workspace: flag(256B) + q(4M) + k(4M) + vt(32M) + xbf(32M) + wall(0.64M)
    int*    flag = (int*)d_ws;
    ushort* q    = (ushort*)((char*)d_ws + 256);
    ushort* kk   = q   + (size_t)B_ * N_ * D_;   // [B, N, 64] bf16
    ushort* vt   = kk  + (size_t)B_ * N_ * D_;   // [B, C, N] bf16
    ushort* xbf  = vt  + (size_t)B_ * C_ * N_;   // [M, C] bf16
    ushort* wall = xbf + (size_t)B_ * N_ * C_;   // [640, C] bf16 (Wq|Wk|Wv)

    probe_kernel<<<1, 64, 0, stream>>>(x, flag);
    convert_kernel<<<2048, 256, 0, stream>>>(x, Wq, Wk, Wv, xbf, wall, flag);

    // merged projection GEMM: M=32768, N=640 (64 q | 64 k | 512 v), K=512
    // 1D grid + XCD swizzle (1280 = 8 x 160; same-m n-tiles on one XCD)
    proj_all<<<dim3(1280), 256, 0, stream>>>(
        xbf, wall, bq, bk, bv, q, kk, vt, flag);

    // two half-batch dispatches: surfaces proj_all in the rocprof top-5
    attn_fused<<<dim3(N_ / 64, 2, 8), 512, 0, stream>>>(
        q, kk, vt, x, gamma, d_out, flag, 0);
    attn_fused<<<dim3(N_ / 64, 2, 8), 512, 0, stream>>>(
        q, kk, vt, x, gamma, d_out, flag, 8);
}